// Round 6
// baseline (904.764 us; speedup 1.0000x reference)
//
#include <hip/hip_runtime.h>
#include <cstdint>
#include <cstddef>

// ---------------------------------------------------------------------------
// FullyDynamicSTGNN: GAT(128 nodes, T=64, B=32) -> 2-layer Transformer(d=2048)
// -> linear head.  Heavy GEMMs in bf16 MFMA (16x16x32), everything else fp32.
// R9: QKV fused into ONE N=6144 GEMM with a 256x256 tile / 512 threads /
//     8 waves (wave-tile 128x64 -> 32 MFMA per K-step per wave, 2x the MFMA
//     density of the 128-tile kernels).  Same 3-ring counted-vmcnt skeleton.
//     Wt0..2 are contiguous => Bt is a 6144x2048 view for free; C is a single
//     QKV buffer (stride 6144), attn adjusted.  Split-K reverted (proven null).
//     GAT / thin GEMMs / transposes unchanged.
// ---------------------------------------------------------------------------

typedef unsigned short u16;
typedef __bf16 bf16x8 __attribute__((ext_vector_type(8)));
typedef float f32x4 __attribute__((ext_vector_type(4)));
typedef float f32x2 __attribute__((ext_vector_type(2)));
typedef unsigned int u32x4 __attribute__((ext_vector_type(4)));
typedef float f32x4v __attribute__((ext_vector_type(4)));
typedef unsigned short u16x4 __attribute__((ext_vector_type(4)));

__device__ __forceinline__ u16 f2b(float f) {
  union { float f; unsigned u; } x; x.f = f;
  unsigned r = x.u + 0x7fffu + ((x.u >> 16) & 1u);   // RNE
  return (u16)(r >> 16);
}
__device__ __forceinline__ float b2f(u16 s) {
  union { unsigned u; float f; } x; x.u = ((unsigned)s) << 16;
  return x.f;
}
__device__ __forceinline__ float b2f_lo(unsigned q) {
  union { unsigned u; float f; } x; x.u = q << 16;
  return x.f;
}
__device__ __forceinline__ float b2f_hi(unsigned q) {
  union { unsigned u; float f; } x; x.u = q & 0xffff0000u;
  return x.f;
}

// async global->LDS, 16B per lane; lds dest must be wave-uniform base (+lane*16)
__device__ __forceinline__ void gload_lds16(const void* g, void* l) {
  __builtin_amdgcn_global_load_lds(
      (const __attribute__((address_space(1))) unsigned int*)g,
      (__attribute__((address_space(3))) unsigned int*)l, 16, 0, 0);
}

// ---------------------------------------------------------------------------
// GAT kernel: one 1024-thread block per (b,t) graph.  (unchanged from R8)
// ---------------------------------------------------------------------------
__global__ __launch_bounds__(1024) void gat_kernel(
    const float* __restrict__ X, const float* __restrict__ V_Adap,
    const int* __restrict__ class_idx,
    const float* __restrict__ Wl, const float* __restrict__ bl,
    const float* __restrict__ Wr, const float* __restrict__ br,
    const float* __restrict__ att, const float* __restrict__ gat_bias,
    const float* __restrict__ Wfc, const float* __restrict__ bfc,
    float* __restrict__ h_f32, u16* __restrict__ h_b16)
{
  const int bt = blockIdx.x;
  const int tid = threadIdx.x;

  __shared__ __align__(16) float xlT[64 * 132];     // 33792
  __shared__ __align__(16) float xrT[64 * 132];     // 33792
  __shared__ __align__(16) u16   xlTb[64 * 136];    // 17408
  __shared__ __align__(16) u16   esbT[128 * 136];   // 34816
  __shared__ __align__(16) u16   aggb[128 * 72];    // 18432 (X scratch / p-partials)
  __shared__ __align__(16) float WlT[64 * 20];      // 5120  [h][f]
  __shared__ __align__(16) float WrT[64 * 20];      // 5120
  __shared__ __align__(16) float WfcT[16 * 66];     // 4224  [s][h]
  __shared__ float atts[64], bls[64], brs[64], gbias[64], bfcs[16];
  __shared__ float cls[128], crs[128], inv_s[128];
  __shared__ float red[8 * 128];                    // 4096

  float* scratchX = (float*)aggb;   // 8KB of 18KB; aggb unused until stage 5
  float* red2 = (float*)aggb;       // 16x128 f32 p-partials (stage 3 use)

  // --- stage 0: load weights + stage X row-block into LDS ---
  {
    const int h = tid >> 4, f = tid & 15;
    WlT[h * 20 + f] = Wl[f * 64 + h];
    WrT[h * 20 + f] = Wr[f * 64 + h];
    WfcT[f * 66 + h] = Wfc[h * 16 + f];    // f plays 's' here
  }
  if (tid < 64) { atts[tid] = att[tid]; bls[tid] = bl[tid]; brs[tid] = br[tid]; gbias[tid] = gat_bias[tid]; }
  if (tid < 16) bfcs[tid] = bfc[tid];
  if (tid < 512)
    ((f32x4*)scratchX)[tid] = ((const f32x4*)(X + (size_t)bt * 2048))[tid];
  const int cidx = *class_idx;
  __syncthreads();

  // --- stage 1: xl = x@Wl+bl, xr = x@Wr+br.  (h = lane, node-group = wave) ---
  {
    const int h = tid & 63, ng = tid >> 6;        // ng == wave id (uniform)
    f32x4 wl4[4], wr4[4];
    #pragma unroll
    for (int f4 = 0; f4 < 4; f4++) {
      wl4[f4] = *(const f32x4*)&WlT[h * 20 + f4 * 4];
      wr4[f4] = *(const f32x4*)&WrT[h * 20 + f4 * 4];
    }
    const float blh = bls[h], brh = brs[h];
    float al8[8], ar8[8];
    #pragma unroll
    for (int t = 0; t < 8; t++) {
      const int n = ng * 8 + t;
      float al = blh, ar = brh;
      #pragma unroll
      for (int f4 = 0; f4 < 4; f4++) {
        const f32x4 xv = *(const f32x4*)&scratchX[n * 16 + f4 * 4];  // broadcast
        #pragma unroll
        for (int f = 0; f < 4; f++) {
          al = fmaf(xv[f], wl4[f4][f], al);
          ar = fmaf(xv[f], wr4[f4][f], ar);
        }
      }
      al8[t] = al; ar8[t] = ar;
    }
    *(f32x4*)&xlT[h * 132 + ng * 8]     = *(f32x4*)&al8[0];
    *(f32x4*)&xlT[h * 132 + ng * 8 + 4] = *(f32x4*)&al8[4];
    *(f32x4*)&xrT[h * 132 + ng * 8]     = *(f32x4*)&ar8[0];
    *(f32x4*)&xrT[h * 132 + ng * 8 + 4] = *(f32x4*)&ar8[4];
    u16 pb[8];
    #pragma unroll
    for (int t = 0; t < 8; t++) pb[t] = f2b(al8[t]);
    *(u16x4*)&xlTb[h * 136 + ng * 8]     = *(u16x4*)&pb[0];
    *(u16x4*)&xlTb[h * 136 + ng * 8 + 4] = *(u16x4*)&pb[4];
  }
  __syncthreads();

  // --- stage 2: cl[n] = att.xl[n], cr[n] = att.xr[n] (1024-thread partials) ---
  {
    const int n = tid & 127, g = tid >> 7;        // g 0..7
    const float* srcT = (g < 4) ? xlT : xrT;
    const int h0 = (g & 3) * 16;
    float s = 0.f;
    #pragma unroll
    for (int hh = 0; hh < 16; hh++)
      s = fmaf(atts[h0 + hh], srcT[(h0 + hh) * 132 + n], s);
    red[g * 128 + n] = s;
  }
  __syncthreads();
  if (tid < 256) {
    const int n = tid & 127;
    const int base = (tid < 128) ? 0 : 4;
    const float s = ((red[base * 128 + n] + red[(base + 1) * 128 + n])
                   + red[(base + 2) * 128 + n]) + red[(base + 3) * 128 + n];
    if (tid < 128) cls[n] = s; else crs[n] = s;
  }
  __syncthreads();

  // --- stage 3: e[i][j] -> p = exp(e) (bf16) -> esbT[j][i]; per-wave row
  //     partial sums -> red2[w][j].  8x2 tile, i0 wave-uniform. ---
  {
    const int w = tid >> 6;
    const int i0 = w * 8;                 // wave-uniform, 0..120
    const int j0 = (tid & 63) * 2;        // 0..126
    float acc[8][2] = {};
    #pragma unroll 8
    for (int h = 0; h < 64; h++) {
      const float ah = att[h];            // uniform -> s_load (SGPR)
      const f32x4 xa0 = *(const f32x4*)&xlT[h * 132 + i0];       // broadcast
      const f32x4 xa1 = *(const f32x4*)&xlT[h * 132 + i0 + 4];   // broadcast
      const f32x2 xb  = *(const f32x2*)&xrT[h * 132 + j0];
      #pragma unroll
      for (int a = 0; a < 4; a++) {
        acc[a][0]     = fmaf(ah, __builtin_fabsf(xa0[a] + xb[0]), acc[a][0]);
        acc[a][1]     = fmaf(ah, __builtin_fabsf(xa0[a] + xb[1]), acc[a][1]);
        acc[4 + a][0] = fmaf(ah, __builtin_fabsf(xa1[a] + xb[0]), acc[4 + a][0]);
        acc[4 + a][1] = fmaf(ah, __builtin_fabsf(xa1[a] + xb[1]), acc[4 + a][1]);
      }
    }
    const float* Vc = V_Adap + (size_t)cidx * 16384;
    float vm[8][2];
    #pragma unroll
    for (int a = 0; a < 8; a++) {
      const f32x2 vc = *(const f32x2*)&Vc[(size_t)(i0 + a) * 128 + j0];
      vm[a][0] = vc[0]; vm[a][1] = vc[1];
    }
    const f32x4 cl0 = *(const f32x4*)&cls[i0];
    const f32x4 cl1 = *(const f32x4*)&cls[i0 + 4];
    float cli[8] = {cl0[0], cl0[1], cl0[2], cl0[3], cl1[0], cl1[1], cl1[2], cl1[3]};
    float psum[2];
    #pragma unroll
    for (int b = 0; b < 2; b++) {
      const int j = j0 + b;
      const float ej = 0.6f * crs[j];
      u16 pk[8];
      float ps = 0.f;
      #pragma unroll
      for (int a = 0; a < 8; a++) {
        const int i = i0 + a;
        const float e = ej + 0.6f * cli[a] + 0.4f * acc[a][b];
        // sigmoid(v)/128 > 0.004  <=>  v > ln(0.512/0.488)
        const bool m = (vm[a][b] > 0.04800922f) || (i == j);
        const float p = m ? __expf(e) : 0.f;
        ps += p;
        pk[a] = f2b(p);
      }
      psum[b] = ps;
      *(u16x4*)&esbT[j * 136 + i0]     = *(u16x4*)&pk[0];
      *(u16x4*)&esbT[j * 136 + i0 + 4] = *(u16x4*)&pk[4];
    }
    *(f32x2*)&red2[w * 128 + j0] = *(f32x2*)&psum[0];
  }
  __syncthreads();
  if (tid < 128) {
    float s = 0.f;
    #pragma unroll
    for (int c = 0; c < 16; c++) s += red2[c * 128 + tid];
    inv_s[tid] = 1.f / s;
  }
  __syncthreads();

  // --- stage 5: agg[j][h] = (1/s_j) sum_i p^T[j][i] xl[i][h]  via MFMA ---
  {
    const int w = tid >> 6, lane = tid & 63;
    const int lq = lane >> 4, lr = lane & 15;
    const int jt = w >> 1, ht0 = (w & 1) * 2;
    f32x4 acc2[2] = {};
    #pragma unroll
    for (int ks = 0; ks < 4; ks++) {
      const bf16x8 af = __builtin_bit_cast(bf16x8,
          *(const u32x4*)&esbT[(jt * 16 + lr) * 136 + ks * 32 + lq * 8]);
      #pragma unroll
      for (int t = 0; t < 2; t++) {
        const bf16x8 bfb = __builtin_bit_cast(bf16x8,
            *(const u32x4*)&xlTb[((ht0 + t) * 16 + lr) * 136 + ks * 32 + lq * 8]);
        acc2[t] = __builtin_amdgcn_mfma_f32_16x16x32_bf16(af, bfb, acc2[t], 0, 0, 0);
      }
    }
    #pragma unroll
    for (int t = 0; t < 2; t++) {
      const int h = (ht0 + t) * 16 + lr;
      const float gb = gbias[h];
      #pragma unroll
      for (int r = 0; r < 4; r++) {
        const int j = jt * 16 + lq * 4 + r;
        aggb[j * 72 + h] = f2b(acc2[t][r] * inv_s[j] + gb);
      }
    }
  }
  __syncthreads();

  // --- stage 6: out = agg @ Wfc + bfc -> h (fp32 + bf16) ---
  {
    const int j = tid >> 3, s0 = (tid & 7) * 2;
    float o0 = bfcs[s0], o1 = bfcs[s0 + 1];
    #pragma unroll
    for (int h8 = 0; h8 < 8; h8++) {
      u32x4 q = *(const u32x4*)&aggb[j * 72 + h8 * 8];
      #pragma unroll
      for (int w2 = 0; w2 < 4; w2++) {
        const int h = h8 * 8 + w2 * 2;
        const float a0 = b2f_lo(q[w2]);
        const float a1 = b2f_hi(q[w2]);
        o0 = fmaf(a0, WfcT[s0 * 66 + h], o0);
        o1 = fmaf(a0, WfcT[(s0 + 1) * 66 + h], o1);
        o0 = fmaf(a1, WfcT[s0 * 66 + h + 1], o0);
        o1 = fmaf(a1, WfcT[(s0 + 1) * 66 + h + 1], o1);
      }
    }
    const size_t off = (size_t)bt * 2048 + j * 16 + s0;
    h_f32[off] = o0; h_f32[off + 1] = o1;
    h_b16[off] = f2b(o0); h_b16[off + 1] = f2b(o1);
  }
}

// ---------------------------------------------------------------------------
// transpose + cast: src (2048 x 2048) fp32 row-major -> dst bf16 (dst[n][k] =
// src[k][n]).  Up to 3 matrices via blockIdx.z.
// ---------------------------------------------------------------------------
struct TransArgs {
  const float* s0; const float* s1; const float* s2;
  u16* d0; u16* d1; u16* d2;
};

__global__ __launch_bounds__(256) void transpose_cast(TransArgs p)
{
  const float* src = (blockIdx.z == 0) ? p.s0 : (blockIdx.z == 1) ? p.s1 : p.s2;
  u16* dst = (blockIdx.z == 0) ? p.d0 : (blockIdx.z == 1) ? p.d1 : p.d2;
  __shared__ u16 tile[64][66];
  const int k0 = blockIdx.y * 64, n0 = blockIdx.x * 64;
  const int tid = threadIdx.x;
  const int c = tid & 63, rb = tid >> 6;
  #pragma unroll
  for (int r = 0; r < 16; r++) {
    const int k = rb + r * 4;
    tile[k][c] = f2b(src[(size_t)(k0 + k) * 2048 + n0 + c]);
  }
  __syncthreads();
  #pragma unroll
  for (int r = 0; r < 16; r++) {
    const int n = rb + r * 4;
    dst[(size_t)(n0 + n) * 2048 + k0 + c] = tile[c][n];
  }
}

// ---------------------------------------------------------------------------
// Fused QKV GEMM: C[m][n] = sum_k A[m][k] * Bt[n][k] + bias_seg[n%2048]
// A: 2048x2048 bf16 (h), Bt: 6144x2048 bf16 (Wt0|Wt1|Wt2 contiguous),
// C: 2048x6144 bf16 (Q|K|V column segments).
// 256x256 tile, 512 threads / 8 waves (2M x 4N -> wave-tile 128x64 ->
// 32 MFMA per wave per K-step vs 12 ds_read_b128: 2x density of 128-tile).
// 3-ring BK=32 (96KB LDS, 1 block/CU), counted vmcnt(8/4/0), barrier pair,
// setprio around compute.  Grid (24, 8) = 192 blocks, XCD-chunked (3 n-strips
// per XCD -> 3MB B-slice fits the 4MB XCD L2).
// ---------------------------------------------------------------------------
__global__ __launch_bounds__(512) void qkv_gemm(
    const u16* __restrict__ A, const u16* __restrict__ Bt,
    const float* __restrict__ bq, const float* __restrict__ bk,
    const float* __restrict__ bv, u16* __restrict__ C)
{
  const int K = 2048;
  // XCD chunking: lin 0..191, xcd = lin&7 gets 24 consecutive blocks
  const int lin = blockIdx.y * 24 + blockIdx.x;
  const int xc = lin & 7, xt = lin >> 3;          // xt 0..23
  const int wx = xc * 3 + (xt >> 3);              // n-tile 0..23
  const int wy = xt & 7;                          // m-tile 0..7
  const int m0 = wy * 256, n0 = wx * 256;

  __shared__ __align__(16) u16 As[3][256 * 32];   // 48KB
  __shared__ __align__(16) u16 Bs[3][256 * 32];   // 48KB

  const int tid = threadIdx.x;
  const int lane = tid & 63, w = tid >> 6;        // 8 waves
  // staging: wave w covers rows [w*32, w*32+32); 4 lanes x 16B per row of 64B.
  const int srow = w * 32 + (lane >> 2);
  const int scol = ((lane & 3) ^ ((lane >> 2) & 3)) * 8;  // pre-swizzled global col
  const u16* gA = A + (size_t)(m0 + srow) * K + scol;
  const u16* gB = Bt + (size_t)(n0 + srow) * K + scol;
  const int lbase = (w * 32) * 32;

  const int wm = (w >> 2) * 128, wn = (w & 3) * 64;
  const int lq = lane >> 4, lr = lane & 15;
  const int csw = (lr & 3) << 3;                  // read-side XOR (elements)

  f32x4 acc[8][4] = {};
  const int NT = K >> 5;                          // 64

  auto stage = [&](int buf, int kt) {
    const int kk = kt << 5;
    #pragma unroll
    for (int c = 0; c < 2; c++) {
      gload_lds16(gA + (size_t)(c * 16) * K + kk, &As[buf][lbase + c * 16 * 32]);
      gload_lds16(gB + (size_t)(c * 16) * K + kk, &Bs[buf][lbase + c * 16 * 32]);
    }
  };
  auto compute = [&](int buf) {
    bf16x8 bfr[4];
    #pragma unroll
    for (int i = 0; i < 4; i++)
      bfr[i] = __builtin_bit_cast(bf16x8,
          *(const u32x4*)&Bs[buf][(wn + i * 16 + lr) * 32 + ((lq * 8) ^ csw)]);
    #pragma unroll
    for (int mi = 0; mi < 8; mi++) {
      const bf16x8 af = __builtin_bit_cast(bf16x8,
          *(const u32x4*)&As[buf][(wm + mi * 16 + lr) * 32 + ((lq * 8) ^ csw)]);
      #pragma unroll
      for (int ni = 0; ni < 4; ni++)
        acc[mi][ni] = __builtin_amdgcn_mfma_f32_16x16x32_bf16(af, bfr[ni], acc[mi][ni], 0, 0, 0);
    }
  };

  stage(0, 0);
  stage(1, 1);
  int cA = 0;                          // buffer holding tile kt
  for (int kt = 0; kt < NT; ++kt) {
    if (kt + 2 < NT) {
      int b2 = cA + 2; if (b2 >= 3) b2 -= 3;
      stage(b2, kt + 2);
      asm volatile("s_waitcnt vmcnt(8)" ::: "memory");
    } else if (kt + 1 < NT) {
      asm volatile("s_waitcnt vmcnt(4)" ::: "memory");
    } else {
      asm volatile("s_waitcnt vmcnt(0)" ::: "memory");
    }
    __builtin_amdgcn_s_barrier();
    asm volatile("" ::: "memory");
    __builtin_amdgcn_s_setprio(1);
    compute(cA);
    __builtin_amdgcn_s_setprio(0);
    asm volatile("" ::: "memory");
    __builtin_amdgcn_s_barrier();
    asm volatile("" ::: "memory");
    if (++cA == 3) cA = 0;
  }

  // epilogue: bias segment is block-uniform (2048 % 256 == 0)
  const int seg = n0 >> 11;
  const float* bias = (seg == 0) ? bq : (seg == 1) ? bk : bv;
  const int nloc0 = (n0 & 2047) + wn;
  #pragma unroll
  for (int ni = 0; ni < 4; ni++) {
    const float bvv = bias[nloc0 + ni * 16 + lr];
    const int col = n0 + wn + ni * 16 + lr;
    #pragma unroll
    for (int mi = 0; mi < 8; mi++) {
      #pragma unroll
      for (int r = 0; r < 4; r++) {
        const int row = m0 + wm + mi * 16 + lq * 4 + r;
        C[(size_t)row * 6144 + col] = f2b(acc[mi][ni][r] + bvv);
      }
    }
  }
}

// ---------------------------------------------------------------------------
// 128(M) x 64(N) tile, BK=64, 3-buf (72KB LDS, 2 blocks/CU).  Full-K.
// L = 6 -> vmcnt 12/6/0.  MODE 0: fp32 out ; 2: bf16 + relu.
// ---------------------------------------------------------------------------
struct GemmArgs {
  const u16* A;
  const u16* Bt0; const u16* Bt1; const u16* Bt2;
  const float* b0; const float* b1; const float* b2;
  void* C0; void* C1; void* C2;
  int N; int K;
};

template <int MODE>
__global__ __launch_bounds__(256) void gemm_bt64(GemmArgs g)
{
  const u16* Bt = g.Bt0;
  const float* bias = g.b0;
  void* C = g.C0;
  const int N = g.N, K = g.K;
  // XCD swizzle: 32x16 grid -> XCD c gets an 8x8 chunk (c = lin%8)
  const int lin = blockIdx.y * 32 + blockIdx.x;
  const int xc = lin & 7, xt = lin >> 3;           // xt 0..63
  const int wx = (xc & 3) * 8 + (xt & 7);
  const int wy = (xc >> 2) * 8 + (xt >> 3);
  const int m0 = wy * 128, n0 = wx * 64;

  __shared__ __align__(16) u16 As[3][128 * 64];   // 48KB
  __shared__ __align__(16) u16 Bs[3][64 * 64];    // 24KB

  const int tid = threadIdx.x;
  const int lane = tid & 63, w = tid >> 6;
  const int srow = w * 8 + (lane >> 3);
  const int scol = ((lane & 7) ^ (lane >> 3)) * 8;   // pre-swizzled global col
  const u16* gA = g.A + (size_t)(m0 + srow) * K + scol;
  const u16* gB = Bt + (size_t)(n0 + srow) * K + scol;
  const int lbase = (w * 8) * 64;

  const int wm = w * 32;
  const int lq = lane >> 4, lr = lane & 15;
  const int csw = (lr & 7) << 3;                  // read-side XOR (elements)

  f32x4 acc[2][4] = {};
  const int NT = K >> 6;

  auto stage = [&](int buf, int kt) {
    const int kk = kt << 6;
    #pragma unroll
    for (int c = 0; c < 4; c++)
      gload_lds16(gA + (size_t)(c * 32) * K + kk, &As[buf][lbase + c * 32 * 64]);
    #pragma unroll
    for (int c = 0; c < 2; c++)
      gload_lds16(gB + (size_t)(c * 32) * K + kk, &Bs[buf][lbase + c * 32 * 64]);
  };
  auto compute = [&](int buf) {
    #pragma unroll
    for (int ks = 0; ks < 2; ks++) {
      bf16x8 af[2], bfr[4];
      #pragma unroll
      for (int i = 0; i < 2; i++)
        af[i] = __builtin_bit_cast(bf16x8,
            *(const u32x4*)&As[buf][(wm + i * 16 + lr) * 64 + ((ks * 32 + lq * 8) ^ csw)]);
      #pragma unroll
      for (int i = 0; i < 4; i++)
        bfr[i] = __builtin_bit_cast(bf16x8,
            *(const u32x4*)&Bs[buf][(i * 16 + lr) * 64 + ((ks * 32 + lq * 8) ^ csw)]);
      #pragma unroll
      for (int mi = 0; mi < 2; mi++)
        #pragma unroll
        for (int ni = 0; ni < 4; ni++)
          acc[mi][ni] = __builtin_amdgcn_mfma_f32_16x16x32_bf16(af[mi], bfr[ni], acc[mi][ni], 0, 0, 0);
    }
  };

  stage(0, 0);
  stage(1, 1);
  int cA = 0;
  for (int kt = 0; kt < NT; ++kt) {
    if (kt + 2 < NT) {
      int b2 = cA + 2; if (b2 >= 3) b2 -= 3;
      stage(b2, kt + 2);
      asm volatile("s_waitcnt vmcnt(12)" ::: "memory");
    } else if (kt + 1 < NT) {
      asm volatile("s_waitcnt vmcnt(6)" ::: "memory");
    } else {
      asm volatile("s_waitcnt vmcnt(0)" ::: "memory");
    }
    __builtin_amdgcn_s_barrier();
    asm volatile("" ::: "memory");
    __builtin_amdgcn_s_setprio(1);
    compute(cA);
    __builtin_amdgcn_s_setprio(0);
    asm volatile("" ::: "memory");
    __builtin_amdgcn_s_barrier();
    asm volatile("" ::: "memory");
    if (++cA == 3) cA = 0;
  }

  #pragma unroll
  for (int ni = 0; ni < 4; ni++) {
    const int col = n0 + ni * 16 + lr;
    const float bv = bias[col];
    #pragma unroll
    for (int mi = 0; mi < 2; mi++) {
      #pragma unroll
      for (int r = 0; r < 4; r++) {
        const int row = m0 + wm + mi * 16 + lq * 4 + r;
        float v = acc[mi][ni][r] + bv;
        if (MODE == 0) {
          ((float*)C)[(size_t)row * N + col] = v;
        } else {
          if (MODE == 2) v = fmaxf(v, 0.f);
          ((u16*)C)[(size_t)row * N + col] = f2b(v);
        }
      }
    }
  }
}

// ---------------------------------------------------------------------------
// attention: one block per (head, batch).  S=64, DH=128.
// R9: reads from fused QKV buffer (row stride 6144; Q|K|V at +0/+2048/+4096).
// QK^T via MFMA (raw bf16 staging, stride 136 conflict-free), fp32 softmax+PV.
// ---------------------------------------------------------------------------
__global__ __launch_bounds__(256) void attn_kernel(
    const u16* __restrict__ QKV, u16* __restrict__ AOb)
{
  const int head = blockIdx.x, b = blockIdx.y;
  const int tid = threadIdx.x;
  __shared__ __align__(16) u16   qs16[64 * 136];   // 17408
  __shared__ __align__(16) u16   ks16[64 * 136];   // 17408
  __shared__ __align__(16) float vs[64 * 128];     // 32768
  __shared__ __align__(16) float ss[64 * 65];      // 16640
  const size_t qbase = ((size_t)b * 64) * 6144 + (size_t)head * 128;
  const size_t obase = ((size_t)b * 64) * 2048 + (size_t)head * 128;

  for (int idx = tid; idx < 1024; idx += 256) {
    const int t_ = idx >> 4, d8 = (idx & 15) * 8;
    const size_t gp = qbase + (size_t)t_ * 6144 + d8;
    const u32x4 q = *(const u32x4*)(QKV + gp);
    const u32x4 k = *(const u32x4*)(QKV + gp + 2048);
    const u32x4 v = *(const u32x4*)(QKV + gp + 4096);
    *(u32x4*)&qs16[t_ * 136 + d8] = q;
    *(u32x4*)&ks16[t_ * 136 + d8] = k;
    f32x4 v0 = {b2f_lo(v[0]), b2f_hi(v[0]), b2f_lo(v[1]), b2f_hi(v[1])};
    f32x4 v1 = {b2f_lo(v[2]), b2f_hi(v[2]), b2f_lo(v[3]), b2f_hi(v[3])};
    *(f32x4*)&vs[t_ * 128 + d8] = v0; *(f32x4*)&vs[t_ * 128 + d8 + 4] = v1;
  }
  __syncthreads();

  // --- QK^T via MFMA: wave w owns S cols j in [w*16, w*16+16) ---
  {
    const int w = tid >> 6, lane = tid & 63;
    const int lq = lane >> 4, lr = lane & 15;
    f32x4 acc4[4] = {};
    #pragma unroll
    for (int ks = 0; ks < 4; ks++) {
      const bf16x8 kf = __builtin_bit_cast(bf16x8,
          *(const u32x4*)&ks16[(w * 16 + lr) * 136 + ks * 32 + lq * 8]);
      #pragma unroll
      for (int mi = 0; mi < 4; mi++) {
        const bf16x8 qf = __builtin_bit_cast(bf16x8,
            *(const u32x4*)&qs16[(mi * 16 + lr) * 136 + ks * 32 + lq * 8]);
        acc4[mi] = __builtin_amdgcn_mfma_f32_16x16x32_bf16(qf, kf, acc4[mi], 0, 0, 0);
      }
    }
    const float sc = 0.08838834764831845f;  // 1/sqrt(128)
    #pragma unroll
    for (int mi = 0; mi < 4; mi++)
      #pragma unroll
      for (int r = 0; r < 4; r++)
        ss[(mi * 16 + lq * 4 + r) * 65 + w * 16 + lr] = acc4[mi][r] * sc;
  }
  __syncthreads();

  {
    const int row = tid >> 2;
    float* rp = &ss[row * 65 + (tid & 3) * 16];
    float mx = -3e38f;
    #pragma unroll
    for (int j = 0; j < 16; j++) mx = fmaxf(mx, rp[j]);
    mx = fmaxf(mx, __shfl_xor(mx, 1, 64));
    mx = fmaxf(mx, __shfl_xor(mx, 2, 64));
    float s = 0.f;
    #pragma unroll
    for (int j = 0; j < 16; j++) { const float p = __expf(rp[j] - mx); rp[j] = p; s += p; }
    s += __shfl_xor(s, 1, 64);
    s += __shfl_xor(s, 2, 64);
    const float inv = 1.f / s;
    #pragma unroll
    for (int j = 0; j < 16; j++) rp[j] *= inv;
  }
  __syncthreads();

  {
    const int i0 = (tid >> 4) * 4, d0 = (tid & 15) * 8;
    float o[4][8] = {};
    for (int j = 0; j < 64; j++) {
      float pv[4];
      #pragma unroll
      for (int a = 0; a < 4; a++) pv[a] = ss[(i0 + a) * 65 + j];
      f32x4v v0 = *(const f32x4v*)&vs[j * 128 + d0];
      f32x4v v1 = *(const f32x4v*)&vs[j * 128 + d0 + 4];
      float vv[8] = {v0[0], v0[1], v0[2], v0[3], v1[0], v1[1], v1[2], v1[3]};
      #pragma unroll
      for (int a = 0; a < 4; a++)
        #pragma unroll
        for (int c = 0; c < 8; c++)
          o[a][c] = fmaf(pv[a], vv[c], o[a][c]);
    }
    #pragma unroll
    for (int a = 0; a < 4; a++)
      #pragma unroll
      for (int c = 0; c < 8; c++)
        AOb[obase + (size_t)(i0 + a) * 2048 + d0 + c] = f2b(o[a][c]);
  }
}

// ---------------------------------------------------------------------------
// fused residual + layernorm: h = LN(hin + delta) ; writes fp32 + bf16
// ---------------------------------------------------------------------------
__global__ __launch_bounds__(256) void ln_kernel(
    const float* __restrict__ hin, const float* __restrict__ delta,
    const float* __restrict__ gamma, const float* __restrict__ beta,
    float* __restrict__ hout, u16* __restrict__ bout_)
{
  const int token = blockIdx.x, tid = threadIdx.x;
  const size_t off = (size_t)token * 2048;
  __shared__ float red[8];
  f32x4 v[2];
  float s = 0.f;
  #pragma unroll
  for (int r = 0; r < 2; r++) {
    const int i = r * 1024 + tid * 4;
    const f32x4 a = *(const f32x4*)(hin + off + i);
    const f32x4 b = *(const f32x4*)(delta + off + i);
    v[r] = a + b;
    s += v[r][0] + v[r][1] + v[r][2] + v[r][3];
  }
  #pragma unroll
  for (int o = 32; o > 0; o >>= 1) s += __shfl_down(s, o, 64);
  if ((tid & 63) == 0) red[tid >> 6] = s;
  __syncthreads();
  const float mean = (red[0] + red[1] + red[2] + red[3]) * (1.f / 2048.f);
  float s2 = 0.f;
  #pragma unroll
  for (int r = 0; r < 2; r++)
    #pragma unroll
    for (int e = 0; e < 4; e++) { const float d = v[r][e] - mean; s2 = fmaf(d, d, s2); }
  #pragma unroll
  for (int o = 32; o > 0; o >>= 1) s2 += __shfl_down(s2, o, 64);
  if ((tid & 63) == 0) red[4 + (tid >> 6)] = s2;
  __syncthreads();
  const float var = (red[4] + red[5] + red[6] + red[7]) * (1.f / 2048.f);
  const float rstd = rsqrtf(var + 1e-5f);
  #pragma unroll
  for (int r = 0; r < 2; r++) {
    const int i = r * 1024 + tid * 4;
    const f32x4 gm = *(const f32x4*)(gamma + i);
    const f32x4 bt = *(const f32x4*)(beta + i);
    f32x4 y;
    u16x4 pb;
    #pragma unroll
    for (int e = 0; e < 4; e++) {
      y[e] = (v[r][e] - mean) * rstd * gm[e] + bt[e];
      pb[e] = f2b(y[e]);
    }
    *(f32x4*)(hout + off + i) = y;
    *(u16x4*)(bout_ + off + i) = pb;
  }
}

// ---------------------------------------------------------------------------
// head: out[b][o] = h[b, T-1, :] . Wout[:, o] + bout[o]
// ---------------------------------------------------------------------------
__global__ __launch_bounds__(256) void final_kernel(
    const float* __restrict__ h, const float* __restrict__ Wout,
    const float* __restrict__ bout, float* __restrict__ out)
{
  const int b = blockIdx.x, tid = threadIdx.x;
  __shared__ float row[2048];
  __shared__ float part[256];
  const float* hr = h + ((size_t)b * 64 + 63) * 2048;
  for (int i = tid; i < 2048; i += 256) row[i] = hr[i];
  __syncthreads();
  const int o = tid & 15, ch = tid >> 4;
  float s = 0.f;
  if (o < 10) {
    const int i0 = ch * 128;
    for (int i = i0; i < i0 + 128; i++) s = fmaf(row[i], Wout[(size_t)i * 10 + o], s);
  }
  part[tid] = s;
  __syncthreads();
  if (tid < 10) {
    float t = bout[tid];
    for (int c2 = 0; c2 < 16; c2++) t += part[c2 * 16 + tid];
    out[(size_t)b * 10 + tid] = t;
  }
}

// ---------------------------------------------------------------------------
extern "C" void kernel_launch(void* const* d_in, const int* in_sizes, int n_in,
                              void* d_out, int out_size, void* d_ws, size_t ws_size,
                              hipStream_t stream)
{
  const float* X        = (const float*)d_in[0];
  const float* V_Adap   = (const float*)d_in[1];
  const float* Wl       = (const float*)d_in[2];
  const float* bl       = (const float*)d_in[3];
  const float* Wr       = (const float*)d_in[4];
  const float* br       = (const float*)d_in[5];
  const float* att      = (const float*)d_in[6];
  const float* gat_bias = (const float*)d_in[7];
  const float* Wfc      = (const float*)d_in[8];
  const float* bfc      = (const float*)d_in[9];
  const float* Wq       = (const float*)d_in[10];
  const float* bq       = (const float*)d_in[11];
  const float* Wk       = (const float*)d_in[12];
  const float* bk       = (const float*)d_in[13];
  const float* Wv       = (const float*)d_in[14];
  const float* bv       = (const float*)d_in[15];
  const float* Wo       = (const float*)d_in[16];
  const float* bo       = (const float*)d_in[17];
  const float* ln1_g    = (const float*)d_in[18];
  const float* ln1_b    = (const float*)d_in[19];
  const float* W1       = (const float*)d_in[20];
  const float* b1       = (const float*)d_in[21];
  const float* W2       = (const float*)d_in[22];
  const float* b2       = (const float*)d_in[23];
  const float* ln2_g    = (const float*)d_in[24];
  const float* ln2_b    = (const float*)d_in[25];
  const float* WoutP    = (const float*)d_in[26];
  const float* boutP    = (const float*)d_in[27];
  const int*   class_idx = (const int*)d_in[28];

  char* ws = (char*)d_ws;
  const size_t MB = (size_t)1 << 20;
  float* h_f32 = (float*)(ws);               // 16 MB  (B*T, D) fp32
  u16*   h_b16 = (u16*)(ws + 16 * MB);       //  8 MB
  u16*   QKVb  = (u16*)(ws + 24 * MB);       // 24 MB  (B*T, 3D) bf16 fused
  u16*   AOb   = (u16*)(ws + 48 * MB);       //  8 MB
  float* tmp   = (float*)(ws + 56 * MB);     // 16 MB  (proj / ff2) fp32
  u16*   ff1b  = (u16*)(ws + 72 * MB);       //  8 MB
  u16*   Wt0   = (u16*)(ws + 80 * MB);       //  8 MB transposed bf16 weights
  u16*   Wt1   = (u16*)(ws + 88 * MB);       //  8 MB  (Wt0..2 contiguous ->
  u16*   Wt2   = (u16*)(ws + 96 * MB);       //  8 MB   6144x2048 Bt view)

  // 1. GAT over all (b,t) graphs -> h (fp32 + bf16)
  gat_kernel<<<2048, 1024, 0, stream>>>(X, V_Adap, class_idx, Wl, bl, Wr, br,
                                        att, gat_bias, Wfc, bfc, h_f32, h_b16);

  const size_t DD = 2048ull * 2048ull;
  for (int l = 0; l < 2; l++) {
    const size_t wofs = (size_t)l * DD;
    const size_t bofs = (size_t)l * 2048;

    // QKV fused: transpose all three weights, then one 2048x6144 GEMM
    transpose_cast<<<dim3(32, 32, 3), 256, 0, stream>>>(
        TransArgs{Wq + wofs, Wk + wofs, Wv + wofs, Wt0, Wt1, Wt2});
    qkv_gemm<<<dim3(24, 8), 512, 0, stream>>>(
        h_b16, Wt0, bq + bofs, bk + bofs, bv + bofs, QKVb);

    attn_kernel<<<dim3(16, 32), 256, 0, stream>>>(QKVb, AOb);

    // o / W1 / W2 transposed together (Wt0..2 free once QKV gemm is done)
    transpose_cast<<<dim3(32, 32, 3), 256, 0, stream>>>(
        TransArgs{Wo + wofs, W1 + wofs, W2 + wofs, Wt0, Wt1, Wt2});

    // out-proj (128x64 tiles, 512 blocks)
    gemm_bt64<0><<<dim3(32, 16), 256, 0, stream>>>(
        GemmArgs{AOb, Wt0, nullptr, nullptr, bo + bofs, nullptr, nullptr,
                 tmp, nullptr, nullptr, 2048, 2048});
    ln_kernel<<<2048, 256, 0, stream>>>(h_f32, tmp, ln1_g + bofs, ln1_b + bofs,
                                        h_f32, h_b16);

    // FF1 (relu, bf16 out)
    gemm_bt64<2><<<dim3(32, 16), 256, 0, stream>>>(
        GemmArgs{h_b16, Wt1, nullptr, nullptr, b1 + bofs, nullptr, nullptr,
                 ff1b, nullptr, nullptr, 2048, 2048});

    // FF2
    gemm_bt64<0><<<dim3(32, 16), 256, 0, stream>>>(
        GemmArgs{ff1b, Wt2, nullptr, nullptr, b2 + bofs, nullptr, nullptr,
                 tmp, nullptr, nullptr, 2048, 2048});
    ln_kernel<<<2048, 256, 0, stream>>>(h_f32, tmp, ln2_g + bofs, ln2_b + bofs,
                                        h_f32, h_b16);
  }

  final_kernel<<<32, 256, 0, stream>>>(h_f32, WoutP, boutP, (float*)d_out);
}